// Round 11
// baseline (705.786 us; speedup 1.0000x reference)
//
#include <hip/hip_runtime.h>
#include <math.h>

#define BB 64
#define CC 768
#define NN 1024
#define BS 192
#define EPS 1e-5f
#define LAM 0.01f

typedef float  f32x4  __attribute__((ext_vector_type(4)));
typedef short  bf16x8 __attribute__((ext_vector_type(8)));

__device__ inline unsigned f2bf(float x) {
    unsigned u = __float_as_uint(x);
    u += 0x7fff + ((u >> 16) & 1);   // RNE
    return u >> 16;
}
__device__ inline unsigned pack2(float r, float i) { return f2bf(r) | (f2bf(i) << 16); }
__device__ inline float bflo(unsigned v) { return __uint_as_float(v << 16); }
__device__ inline float bfhi(unsigned v) { return __uint_as_float(v & 0xffff0000u); }

// LDS bank swizzle on float2 index (FFT kernels only): XOR bits 4-5 into 2-3.
__device__ inline int swz(int i) { return i ^ (((i >> 4) & 3) << 2); }

// ---------------------------------------------------------------------------
// Kernel 1: LayerNorm statistics per (b, n). float4-vectorized along n.
// ---------------------------------------------------------------------------
__global__ __launch_bounds__(512) void ln_stats(const float* __restrict__ x,
                                                float* __restrict__ mu,
                                                float* __restrict__ rstd) {
    int tn = threadIdx.x & 63, tc = threadIdx.x >> 6;   // tc: 0..7
    int n = blockIdx.x * 256 + tn * 4, b = blockIdx.y;
    const float* xp = x + (size_t)b * CC * NN + n;
    f32x4 s = (f32x4)0.f, ss = (f32x4)0.f;
    #pragma unroll 4
    for (int c = tc; c < CC; c += 8) {
        f32x4 v = *(const f32x4*)(xp + (size_t)c * NN);
        s += v; ss += v * v;
    }
    __shared__ f32x4 sm[8][64], sq[8][64];
    sm[tc][tn] = s; sq[tc][tn] = ss;
    __syncthreads();
    if (tc == 0) {
        f32x4 S  = sm[0][tn], SS = sq[0][tn];
        #pragma unroll
        for (int i = 1; i < 8; i++) { S += sm[i][tn]; SS += sq[i][tn]; }
        f32x4 m = S * (1.f / 768.f);
        f32x4 r;
        #pragma unroll
        for (int i = 0; i < 4; i++) {
            float var = SS[i] * (1.f / 768.f) - m[i] * m[i];
            r[i] = rsqrtf(var + EPS);
        }
        *(f32x4*)(mu + (size_t)b * NN + n)   = m;
        *(f32x4*)(rstd + (size_t)b * NN + n) = r;
    }
}

// ---------------------------------------------------------------------------
// Kernel 2: LN-apply + 1024-pt radix-4 DIF FFT (n) + 4-pt DFT (q) + 1/64.
// First stage (L=256) folded into the LN-load.
// ---------------------------------------------------------------------------
__global__ void fwd_fft(const float* __restrict__ x,
                        const float* __restrict__ mu_, const float* __restrict__ rs_,
                        const float* __restrict__ gamma, const float* __restrict__ beta,
                        unsigned* __restrict__ Xp) {
    __shared__ float2 bufs[4][1024];
    int d = blockIdx.x, b = blockIdx.y, tid = threadIdx.x;

    float s1f, c1f;
    __sincosf(-(float)M_PI * 0.5f * (float)tid / 256.f, &s1f, &c1f);
    float c2f = c1f * c1f - s1f * s1f, s2f = 2.f * c1f * s1f;
    float c3f = c2f * c1f - s2f * s1f, s3f = c2f * s1f + s2f * c1f;

    const float* mp = mu_ + b * NN;
    const float* rp = rs_ + b * NN;
    #pragma unroll
    for (int q = 0; q < 4; q++) {
        int c = q * BS + d;
        float g = gamma[c], be = beta[c];
        const float* xp = x + ((size_t)b * CC + c) * NN;
        float v0 = (xp[tid]       - mp[tid])       * rp[tid]       * g + be;
        float v1 = (xp[tid + 256] - mp[tid + 256]) * rp[tid + 256] * g + be;
        float v2 = (xp[tid + 512] - mp[tid + 512]) * rp[tid + 512] * g + be;
        float v3 = (xp[tid + 768] - mp[tid + 768]) * rp[tid + 768] * g + be;
        float t0 = v0 + v2, t1 = v0 - v2, t2 = v1 + v3, t3 = v1 - v3;
        bufs[q][swz(tid)]       = make_float2(t0 + t2, 0.f);
        bufs[q][swz(tid + 256)] = make_float2(t1 * c1f + t3 * s1f, t1 * s1f - t3 * c1f);
        bufs[q][swz(tid + 512)] = make_float2((t0 - t2) * c2f, (t0 - t2) * s2f);
        bufs[q][swz(tid + 768)] = make_float2(t1 * c3f - t3 * s3f, t1 * s3f + t3 * c3f);
    }
    __syncthreads();

    #pragma unroll
    for (int sL = 0; sL < 3; sL++) {
        const int L = 64 >> (2 * sL);
        int j = tid & (L - 1);
        int base = ((tid - j) << 2) + j;
        float s1, c1;
        __sincosf(-(float)M_PI * 0.5f * (float)j / (float)L, &s1, &c1);
        float c2 = c1 * c1 - s1 * s1, s2 = 2.f * c1 * s1;
        float c3 = c2 * c1 - s2 * s1, s3 = c2 * s1 + s2 * c1;
        #pragma unroll
        for (int q = 0; q < 4; q++) {
            float2 a  = bufs[q][swz(base)];
            float2 bb = bufs[q][swz(base + L)];
            float2 cc = bufs[q][swz(base + 2 * L)];
            float2 dd = bufs[q][swz(base + 3 * L)];
            float t0r = a.x + cc.x, t0i = a.y + cc.y;
            float t1r = a.x - cc.x, t1i = a.y - cc.y;
            float t2r = bb.x + dd.x, t2i = bb.y + dd.y;
            float t3r = bb.x - dd.x, t3i = bb.y - dd.y;
            float X0r = t0r + t2r, X0i = t0i + t2i;
            float X2r = t0r - t2r, X2i = t0i - t2i;
            float X1r = t1r + t3i, X1i = t1i - t3r;
            float X3r = t1r - t3i, X3i = t1i + t3r;
            bufs[q][swz(base)]         = make_float2(X0r, X0i);
            bufs[q][swz(base + L)]     = make_float2(X1r * c1 - X1i * s1, X1r * s1 + X1i * c1);
            bufs[q][swz(base + 2 * L)] = make_float2(X2r * c2 - X2i * s2, X2r * s2 + X2i * c2);
            bufs[q][swz(base + 3 * L)] = make_float2(X3r * c3 - X3i * s3, X3r * s3 + X3i * c3);
        }
        __syncthreads();
    }

    float Xr[4][4], Xi[4][4];
    int i0 = swz(4 * tid);
    #pragma unroll
    for (int q = 0; q < 4; q++) {
        const float4* p = (const float4*)&bufs[q][i0];
        float4 u0 = p[0], u1 = p[1];
        float t0r = u0.x + u1.x, t0i = u0.y + u1.y;
        float t1r = u0.x - u1.x, t1i = u0.y - u1.y;
        float t2r = u0.z + u1.z, t2i = u0.w + u1.w;
        float t3r = u0.z - u1.z, t3i = u0.w - u1.w;
        Xr[q][0] = t0r + t2r; Xi[q][0] = t0i + t2i;
        Xr[q][1] = t1r + t3i; Xi[q][1] = t1i - t3r;
        Xr[q][2] = t0r - t2r; Xi[q][2] = t0i - t2i;
        Xr[q][3] = t1r - t3i; Xi[q][3] = t1i + t3r;
    }
    const float sc = 1.f / 64.f;
    unsigned o0[4], o1[4], o2[4], o3[4];
    #pragma unroll
    for (int m = 0; m < 4; m++) {
        float x0r = Xr[0][m], x0i = Xi[0][m];
        float x1r = Xr[1][m], x1i = Xi[1][m];
        float x2r = Xr[2][m], x2i = Xi[2][m];
        float x3r = Xr[3][m], x3i = Xi[3][m];
        float X0r = x0r + x1r + x2r + x3r, X0i = x0i + x1i + x2i + x3i;
        float X2r = x0r - x1r + x2r - x3r, X2i = x0i - x1i + x2i - x3i;
        float X1r = x0r + x1i - x2r - x3i, X1i = x0i - x1r - x2i + x3r;
        float X3r = x0r - x1i - x2r + x3i, X3i = x0i + x1r - x2i - x3r;
        o0[m] = pack2(X0r * sc, X0i * sc);
        o1[m] = pack2(X1r * sc, X1i * sc);
        o2[m] = pack2(X2r * sc, X2i * sc);
        o3[m] = pack2(X3r * sc, X3i * sc);
    }
    size_t qs = (size_t)BS * NN;
    size_t base = (((size_t)b * 4) * BS + d) * NN + 4 * tid;
    *(uint4*)(Xp + base)          = make_uint4(o0[0], o0[1], o0[2], o0[3]);
    *(uint4*)(Xp + base + qs)     = make_uint4(o1[0], o1[1], o1[2], o1[3]);
    *(uint4*)(Xp + base + 2 * qs) = make_uint4(o2[0], o2[1], o2[2], o2[3]);
    *(uint4*)(Xp + base + 3 * qs) = make_uint4(o3[0], o3[1], o3[2], o3[3]);
}

// ---------------------------------------------------------------------------
// Kernel 2b: one-time B prepack into flat [q][ch][j=384][dd=16] dwords.
// ---------------------------------------------------------------------------
__global__ void pack_b(const float* __restrict__ w, unsigned* __restrict__ Bp) {
    int ch = blockIdx.x, q = blockIdx.y;
    const float* wr = w + (size_t)q * BS * BS;
    const float* wi = w + (size_t)(4 + q) * BS * BS;
    size_t base = ((size_t)q * 12 + ch) * (384 * 16);
    for (int r = 0; r < 24; r++) {
        int idx = r * 256 + threadIdx.x;       // 0..6143
        int j = idx >> 4, dd = idx & 15;
        int h = j >> 1;
        int dg = ch * 16 + dd;
        float Wr = wr[(size_t)dg * BS + h];
        float Wi = wi[(size_t)dg * BS + h];
        Bp[base + idx] = (j & 1) ? pack2(Wi, Wr) : pack2(Wr, -Wi);
    }
}

// ---------------------------------------------------------------------------
// Kernel 3: FUSED complex MLP, 512 threads = 8 j-waves, A/H shared LDS panel
// (R10 structure). K-loops now FULLY UNROLLED with a relaxed register cap
// (__launch_bounds__(512, 4) -> ~128 VGPR budget): the scheduler can hoist
// chunk ch+1's three B global loads and A ds_reads above chunk ch's MFMA
// cluster, pipelining the B-latency that bounded R10 (MfmaUtil 30% vs the
// ~44% issue ceiling). No manual prefetch register sets (R8 lesson).
// ---------------------------------------------------------------------------
__global__ __launch_bounds__(512, 4) void fused_mlp(const unsigned* __restrict__ Ap,
                                                    const unsigned* __restrict__ Bp1,
                                                    const unsigned* __restrict__ Bp2,
                                                    const float* __restrict__ b1,
                                                    const float* __restrict__ b2,
                                                    unsigned* __restrict__ Yp) {
    __shared__ __align__(16) unsigned tl[12288];   // 48 KB shared panel

    const int mblk = blockIdx.x;   // 0..15 (64 m each)
    const int bq   = blockIdx.y;   // 0..255
    const int q    = bq & 3;
    const int tid  = threadIdx.x;
    const int wave = tid >> 6;     // 0..7: j-group, owns j = wave*48..+47
    const int lane = tid & 63;
    const int l15  = lane & 15;
    const int quad = lane >> 4;
    const int jw   = wave * 48;

    const size_t bstride = 384 * 16;   // dwords per (q,ch) slab
    const unsigned* b1_lane = Bp1 + (size_t)q * 12 * bstride + (jw + l15) * 16 + quad * 4;
    const unsigned* b2_lane = Bp2 + (size_t)q * 12 * bstride + (jw + l15) * 16 + quad * 4;

    // ---- stage A panel (192 rows x 64 cols) into k-interleaved LDS ----
    {
        const unsigned* abase = Ap + ((size_t)bq * BS) * NN + (size_t)mblk * 64;
        unsigned st[24];
        #pragma unroll
        for (int i = 0; i < 6; i++) {
            int r = (i * 8 + wave) * 4 + quad;
            const unsigned* gp = abase + (size_t)r * NN + l15;
            #pragma unroll
            for (int k = 0; k < 4; k++) st[i * 4 + k] = gp[16 * k];
        }
        #pragma unroll
        for (int i = 0; i < 6; i++) {
            int s = i * 8 + wave;
            unsigned* lp = &tl[s * 256 + quad];
            #pragma unroll
            for (int k = 0; k < 4; k++) lp[(l15 + 16 * k) * 4] = st[i * 4 + k];
        }
    }

    f32x4 acc[3][4];   // acc[tn][tm]
    #pragma unroll
    for (int i = 0; i < 3; i++)
        #pragma unroll
        for (int j = 0; j < 4; j++)
            acc[i][j] = (f32x4)0.f;

    __syncthreads();

    // ---- layer 1: 12 chunks, fully unrolled; A-frags = 1 ds_read_b128 ----
    #pragma unroll
    for (int ch = 0; ch < 12; ch++) {
        const unsigned* tp = &tl[(ch * 4 + quad) * 256];
        const unsigned* bp = b1_lane + ch * bstride;
        bf16x8 af[4], bfr[3];
        #pragma unroll
        for (int tn = 0; tn < 3; tn++) {
            union { uint4 u4; bf16x8 v; } bu;
            bu.u4 = *(const uint4*)(bp + tn * 256);
            bfr[tn] = bu.v;
        }
        #pragma unroll
        for (int tm = 0; tm < 4; tm++)
            af[tm] = *(const bf16x8*)(tp + (tm * 16 + l15) * 4);
        #pragma unroll
        for (int tn = 0; tn < 3; tn++)
            #pragma unroll
            for (int tm = 0; tm < 4; tm++)
                acc[tn][tm] = __builtin_amdgcn_mfma_f32_16x16x32_bf16(bfr[tn], af[tm], acc[tn][tm], 0, 0, 0);
    }

    __syncthreads();   // all waves done reading A before H overwrites

    // ---- epilogue 1: bias + ReLU -> bf16 pack -> H into same LDS ----
    #pragma unroll
    for (int tn = 0; tn < 3; tn++) {
        int hg = jw >> 1;  // wave*24
        hg += tn * 8 + quad * 2;                  // rows hg, hg+1
        float b0r = b1[q * BS + hg];
        float b0i = b1[768 + q * BS + hg];
        float b1r_ = b1[q * BS + hg + 1];
        float b1i_ = b1[768 + q * BS + hg + 1];
        #pragma unroll
        for (int tm = 0; tm < 4; tm++) {
            int c = tm * 16 + l15;
            f32x4 a = acc[tn][tm];
            float v0 = fmaxf(a[0] + b0r, 0.f);
            float v1 = fmaxf(a[1] + b0i, 0.f);
            float v2 = fmaxf(a[2] + b1r_, 0.f);
            float v3 = fmaxf(a[3] + b1i_, 0.f);
            unsigned* hp = &tl[(hg >> 2) * 256 + c * 4 + (hg & 3)];
            *(uint2*)hp = make_uint2(pack2(v0, v1), pack2(v2, v3));
            acc[tn][tm] = (f32x4)0.f;
        }
    }
    __syncthreads();

    // ---- layer 2: 12 chunks over H-LDS, fully unrolled ----
    #pragma unroll
    for (int ch = 0; ch < 12; ch++) {
        const unsigned* tp = &tl[(ch * 4 + quad) * 256];
        const unsigned* bp = b2_lane + ch * bstride;
        bf16x8 af[4], bfr[3];
        #pragma unroll
        for (int tn = 0; tn < 3; tn++) {
            union { uint4 u4; bf16x8 v; } bu;
            bu.u4 = *(const uint4*)(bp + tn * 256);
            bfr[tn] = bu.v;
        }
        #pragma unroll
        for (int tm = 0; tm < 4; tm++)
            af[tm] = *(const bf16x8*)(tp + (tm * 16 + l15) * 4);
        #pragma unroll
        for (int tn = 0; tn < 3; tn++)
            #pragma unroll
            for (int tm = 0; tm < 4; tm++)
                acc[tn][tm] = __builtin_amdgcn_mfma_f32_16x16x32_bf16(bfr[tn], af[tm], acc[tn][tm], 0, 0, 0);
    }

    // ---- epilogue 2: bias + softshrink -> Y plane stores ----
    #pragma unroll
    for (int tn = 0; tn < 3; tn++) {
        int hg = (jw >> 1) + tn * 8 + quad * 2;
        float b0r = b2[q * BS + hg];
        float b0i = b2[768 + q * BS + hg];
        float b1r_ = b2[q * BS + hg + 1];
        float b1i_ = b2[768 + q * BS + hg + 1];
        size_t row0 = ((size_t)bq * BS + hg) * NN + (size_t)mblk * 64;
        #pragma unroll
        for (int tm = 0; tm < 4; tm++) {
            int mcol = tm * 16 + l15;
            f32x4 a = acc[tn][tm];
            float v0 = a[0] + b0r, v1 = a[1] + b0i;
            float v2 = a[2] + b1r_, v3 = a[3] + b1i_;
            v0 = (v0 > LAM) ? (v0 - LAM) : ((v0 < -LAM) ? (v0 + LAM) : 0.f);
            v1 = (v1 > LAM) ? (v1 - LAM) : ((v1 < -LAM) ? (v1 + LAM) : 0.f);
            v2 = (v2 > LAM) ? (v2 - LAM) : ((v2 < -LAM) ? (v2 + LAM) : 0.f);
            v3 = (v3 > LAM) ? (v3 - LAM) : ((v3 < -LAM) ? (v3 + LAM) : 0.f);
            Yp[row0 + mcol]      = pack2(v0, v1);
            Yp[row0 + NN + mcol] = pack2(v2, v3);
        }
    }
}

// ---------------------------------------------------------------------------
// Kernel 4: inverse q-IDFT + radix-4 DIT IFFT + residual. Last stage (L=256)
// folded into the epilogue (real parts only).
// ---------------------------------------------------------------------------
__global__ void inv_fft(const float* __restrict__ x,
                        const unsigned* __restrict__ Yp,
                        float* __restrict__ out) {
    __shared__ float2 bufs[4][1024];
    int d = blockIdx.x, b = blockIdx.y, tid = threadIdx.x;

    float Ar[4][4], Ai[4][4];
    size_t qs = (size_t)BS * NN;
    size_t rowb = (((size_t)b * 4) * BS + d) * NN + 4 * tid;
    #pragma unroll
    for (int q = 0; q < 4; q++) {
        uint4 v = *(const uint4*)(Yp + rowb + (size_t)q * qs);
        Ar[q][0] = bflo(v.x); Ai[q][0] = bfhi(v.x);
        Ar[q][1] = bflo(v.y); Ai[q][1] = bfhi(v.y);
        Ar[q][2] = bflo(v.z); Ai[q][2] = bfhi(v.z);
        Ar[q][3] = bflo(v.w); Ai[q][3] = bfhi(v.w);
    }
    #pragma unroll
    for (int m = 0; m < 4; m++) {
        float x0r = Ar[0][m], x0i = Ai[0][m];
        float x1r = Ar[1][m], x1i = Ai[1][m];
        float x2r = Ar[2][m], x2i = Ai[2][m];
        float x3r = Ar[3][m], x3i = Ai[3][m];
        float Y0r = x0r + x1r + x2r + x3r, Y0i = x0i + x1i + x2i + x3i;
        float Y2r = x0r - x1r + x2r - x3r, Y2i = x0i - x1i + x2i - x3i;
        float Y1r = x0r - x1i - x2r + x3i, Y1i = x0i + x1r - x2i - x3r;
        float Y3r = x0r + x1i - x2r - x3i, Y3i = x0i - x1r - x2i + x3r;
        Ar[0][m] = Y0r; Ai[0][m] = Y0i;
        Ar[1][m] = Y1r; Ai[1][m] = Y1i;
        Ar[2][m] = Y2r; Ai[2][m] = Y2i;
        Ar[3][m] = Y3r; Ai[3][m] = Y3i;
    }
    int i0 = swz(4 * tid);
    #pragma unroll
    for (int q = 0; q < 4; q++) {
        float t0r = Ar[q][0] + Ar[q][2], t0i = Ai[q][0] + Ai[q][2];
        float t1r = Ar[q][0] - Ar[q][2], t1i = Ai[q][0] - Ai[q][2];
        float t2r = Ar[q][1] + Ar[q][3], t2i = Ai[q][1] + Ai[q][3];
        float t3r = Ar[q][1] - Ar[q][3], t3i = Ai[q][1] - Ai[q][3];
        float4* p = (float4*)&bufs[q][i0];
        p[0] = make_float4(t0r + t2r, t0i + t2i, t1r - t3i, t1i + t3r);
        p[1] = make_float4(t0r - t2r, t0i - t2i, t1r + t3i, t1i - t3r);
    }
    __syncthreads();

    #pragma unroll
    for (int sL = 0; sL < 3; sL++) {
        const int L = 4 << (2 * sL);
        int j = tid & (L - 1);
        int base = ((tid - j) << 2) + j;
        float s1, c1;
        __sincosf((float)M_PI * 0.5f * (float)j / (float)L, &s1, &c1);
        float c2 = c1 * c1 - s1 * s1, s2 = 2.f * c1 * s1;
        float c3 = c2 * c1 - s2 * s1, s3 = c2 * s1 + s2 * c1;
        #pragma unroll
        for (int q = 0; q < 4; q++) {
            float2 y0 = bufs[q][swz(base)];
            float2 y1 = bufs[q][swz(base + L)];
            float2 y2 = bufs[q][swz(base + 2 * L)];
            float2 y3 = bufs[q][swz(base + 3 * L)];
            float A1r = y1.x * c1 - y1.y * s1, A1i = y1.x * s1 + y1.y * c1;
            float A2r = y2.x * c2 - y2.y * s2, A2i = y2.x * s2 + y2.y * c2;
            float A3r = y3.x * c3 - y3.y * s3, A3i = y3.x * s3 + y3.y * c3;
            float t0r = y0.x + A2r, t0i = y0.y + A2i;
            float t1r = y0.x - A2r, t1i = y0.y - A2i;
            float t2r = A1r + A3r, t2i = A1i + A3i;
            float t3r = A1r - A3r, t3i = A1i - A3i;
            bufs[q][swz(base)]         = make_float2(t0r + t2r, t0i + t2i);
            bufs[q][swz(base + L)]     = make_float2(t1r - t3i, t1i + t3r);
            bufs[q][swz(base + 2 * L)] = make_float2(t0r - t2r, t0i - t2i);
            bufs[q][swz(base + 3 * L)] = make_float2(t1r + t3i, t1i - t3r);
        }
        __syncthreads();
    }

    float s1f, c1f;
    __sincosf((float)M_PI * 0.5f * (float)tid / 256.f, &s1f, &c1f);
    float c2f = c1f * c1f - s1f * s1f, s2f = 2.f * c1f * s1f;
    float c3f = c2f * c1f - s2f * s1f, s3f = c2f * s1f + s2f * c1f;
    const float sc = 1.f / 64.f;
    #pragma unroll
    for (int q = 0; q < 4; q++) {
        float2 y0 = bufs[q][swz(tid)];
        float2 y1 = bufs[q][swz(tid + 256)];
        float2 y2 = bufs[q][swz(tid + 512)];
        float2 y3 = bufs[q][swz(tid + 768)];
        float A1r = y1.x * c1f - y1.y * s1f, A1i = y1.x * s1f + y1.y * c1f;
        float A2r = y2.x * c2f - y2.y * s2f;
        float A3r = y3.x * c3f - y3.y * s3f, A3i = y3.x * s3f + y3.y * c3f;
        float t0r = y0.x + A2r;
        float t1r = y0.x - A2r;
        float t2r = A1r + A3r;
        float t3i = A1i - A3i;
        size_t row = (((size_t)b * 4 + q) * BS + d) * NN;
        const float* xp = x + row;
        out[row + tid]       = (t0r + t2r) * sc + xp[tid];
        out[row + tid + 256] = (t1r - t3i) * sc + xp[tid + 256];
        out[row + tid + 512] = (t0r - t2r) * sc + xp[tid + 512];
        out[row + tid + 768] = (t1r + t3i) * sc + xp[tid + 768];
    }
}

// ---------------------------------------------------------------------------
extern "C" void kernel_launch(void* const* d_in, const int* in_sizes, int n_in,
                              void* d_out, int out_size, void* d_ws, size_t ws_size,
                              hipStream_t stream) {
    const float* x     = (const float*)d_in[0];
    const float* w1    = (const float*)d_in[1];
    const float* w2    = (const float*)d_in[2];
    const float* b1    = (const float*)d_in[3];
    const float* b2    = (const float*)d_in[4];
    const float* gamma = (const float*)d_in[5];
    const float* beta  = (const float*)d_in[6];

    unsigned* Xp = (unsigned*)d_ws;
    float* mu    = (float*)d_ws + (size_t)BB * CC * NN;
    float* rstd  = mu + (size_t)BB * NN;
    unsigned* Bp1 = (unsigned*)(rstd + (size_t)BB * NN);
    unsigned* Bp2 = Bp1 + (size_t)4 * 12 * 384 * 16;
    unsigned* Yp = Xp;   // layer-2 output overwrites X region (disjoint m-cols per block)

    pack_b<<<dim3(12, 4), 256, 0, stream>>>(w1, Bp1);
    pack_b<<<dim3(12, 4), 256, 0, stream>>>(w2, Bp2);
    ln_stats<<<dim3(NN / 256, BB), 512, 0, stream>>>(x, mu, rstd);
    fwd_fft<<<dim3(BS, BB), 256, 0, stream>>>(x, mu, rstd, gamma, beta, Xp);
    fused_mlp<<<dim3(16, 256), 512, 0, stream>>>(Xp, Bp1, Bp2, b1, b2, Yp);
    inv_fft<<<dim3(BS, BB), 256, 0, stream>>>(x, Yp, (float*)d_out);
}

// Round 12
// 682.925 us; speedup vs baseline: 1.0335x; 1.0335x over previous
//
#include <hip/hip_runtime.h>
#include <math.h>

#define BB 64
#define CC 768
#define NN 1024
#define BS 192
#define EPS 1e-5f
#define LAM 0.01f

typedef float  f32x4  __attribute__((ext_vector_type(4)));
typedef short  bf16x8 __attribute__((ext_vector_type(8)));

__device__ inline unsigned f2bf(float x) {
    unsigned u = __float_as_uint(x);
    u += 0x7fff + ((u >> 16) & 1);   // RNE
    return u >> 16;
}
__device__ inline unsigned pack2(float r, float i) { return f2bf(r) | (f2bf(i) << 16); }
__device__ inline float bflo(unsigned v) { return __uint_as_float(v << 16); }
__device__ inline float bfhi(unsigned v) { return __uint_as_float(v & 0xffff0000u); }

// LDS bank swizzle on float2 index (FFT kernels): XOR bits 4-5 into bits 2-3.
// Bits 0-1 untouched -> swz(4t+j) == swz(4t)+j (4-consec groups stay contiguous).
__device__ inline int swz(int i) { return i ^ (((i >> 4) & 3) << 2); }

// Base-4 digit reversal of a 10-bit index (5 bit-pairs reversed).
// Our radix-4 DIF stores frequency k at position p = rev4(k) (residue u mod 4
// goes to quarter u at every stage), so rev4(position) = frequency.
__device__ inline int rev4(int p) {
    return ((p & 3) << 8) | ((p & 12) << 4) | (p & 48) | ((p >> 4) & 12) | ((p >> 8) & 3);
}
// Partner position holding frequency N-k for the position holding k.
__device__ inline int prt(int p) {
    return rev4((1024 - rev4(p)) & 1023);
}
__device__ inline float2 cmul(float2 z, float c, float s) {
    return make_float2(z.x * c - z.y * s, z.x * s + z.y * c);
}

// ---------------------------------------------------------------------------
// Kernel 1: LayerNorm statistics per (b, n). float4-vectorized along n.
// ---------------------------------------------------------------------------
__global__ __launch_bounds__(512) void ln_stats(const float* __restrict__ x,
                                                float* __restrict__ mu,
                                                float* __restrict__ rstd) {
    int tn = threadIdx.x & 63, tc = threadIdx.x >> 6;   // tc: 0..7
    int n = blockIdx.x * 256 + tn * 4, b = blockIdx.y;
    const float* xp = x + (size_t)b * CC * NN + n;
    f32x4 s = (f32x4)0.f, ss = (f32x4)0.f;
    #pragma unroll 4
    for (int c = tc; c < CC; c += 8) {
        f32x4 v = *(const f32x4*)(xp + (size_t)c * NN);
        s += v; ss += v * v;
    }
    __shared__ f32x4 sm[8][64], sq[8][64];
    sm[tc][tn] = s; sq[tc][tn] = ss;
    __syncthreads();
    if (tc == 0) {
        f32x4 S  = sm[0][tn], SS = sq[0][tn];
        #pragma unroll
        for (int i = 1; i < 8; i++) { S += sm[i][tn]; SS += sq[i][tn]; }
        f32x4 m = S * (1.f / 768.f);
        f32x4 r;
        #pragma unroll
        for (int i = 0; i < 4; i++) {
            float var = SS[i] * (1.f / 768.f) - m[i] * m[i];
            r[i] = rsqrtf(var + EPS);
        }
        *(f32x4*)(mu + (size_t)b * NN + n)   = m;
        *(f32x4*)(rstd + (size_t)b * NN + n) = r;
    }
}

// ---------------------------------------------------------------------------
// Kernel 2: LN-apply + q-DFT-first (real input!) + 2 packed complex 1024-pt
// radix-4 DIF FFTs (was 4) + conjugate-symmetry unpack + 1/64 scale.
// U0,U2 real -> Za = U0 + i*U2 (one FFT); U1 complex (one FFT); U3 = conj(U1)
// derived at partner positions. First stage (L=256) folded into registers.
// ---------------------------------------------------------------------------
__global__ void fwd_fft(const float* __restrict__ x,
                        const float* __restrict__ mu_, const float* __restrict__ rs_,
                        const float* __restrict__ gamma, const float* __restrict__ beta,
                        unsigned* __restrict__ Xp) {
    __shared__ float2 bufs[2][1024];
    int d = blockIdx.x, b = blockIdx.y, tid = threadIdx.x;

    // twiddles for folded L=256 stage (j = tid), W = e^{-i*pi*j/512}
    float s1f, c1f;
    __sincosf(-(float)M_PI * 0.5f * (float)tid / 256.f, &s1f, &c1f);
    float c2f = c1f * c1f - s1f * s1f, s2f = 2.f * c1f * s1f;
    float c3f = c2f * c1f - s2f * s1f, s3f = c2f * s1f + s2f * c1f;

    const float* mp = mu_ + b * NN;
    const float* rp = rs_ + b * NN;

    // LN-apply for all 4 q at n = tid + 256k
    float xv[4][4];
    #pragma unroll
    for (int q = 0; q < 4; q++) {
        int c = q * BS + d;
        float g = gamma[c], be = beta[c];
        const float* xp = x + ((size_t)b * CC + c) * NN;
        #pragma unroll
        for (int k = 0; k < 4; k++) {
            int n = tid + 256 * k;
            xv[q][k] = (xp[n] - mp[n]) * rp[n] * g + be;
        }
    }
    // q-DFT per n (real input): U0=sum, U2=alt-sum (real), U1=(x0-x2)+i(x3-x1)
    float2 za[4], zb[4];
    #pragma unroll
    for (int k = 0; k < 4; k++) {
        float a = xv[0][k], b1v = xv[1][k], c2v = xv[2][k], d3v = xv[3][k];
        za[k] = make_float2(a + b1v + c2v + d3v, a - b1v + c2v - d3v);  // U0 + i*U2
        zb[k] = make_float2(a - c2v, d3v - b1v);                        // U1
    }
    // folded L=256 stage, full complex, both planes
    #pragma unroll
    for (int pl = 0; pl < 2; pl++) {
        float2 z0 = pl ? zb[0] : za[0], z1 = pl ? zb[1] : za[1];
        float2 z2 = pl ? zb[2] : za[2], z3 = pl ? zb[3] : za[3];
        float t0r = z0.x + z2.x, t0i = z0.y + z2.y;
        float t1r = z0.x - z2.x, t1i = z0.y - z2.y;
        float t2r = z1.x + z3.x, t2i = z1.y + z3.y;
        float t3r = z1.x - z3.x, t3i = z1.y - z3.y;
        bufs[pl][swz(tid)] = make_float2(t0r + t2r, t0i + t2i);
        bufs[pl][swz(tid + 256)] = cmul(make_float2(t1r + t3i, t1i - t3r), c1f, s1f); // (t1-i*t3)W
        bufs[pl][swz(tid + 512)] = cmul(make_float2(t0r - t2r, t0i - t2i), c2f, s2f);
        bufs[pl][swz(tid + 768)] = cmul(make_float2(t1r - t3i, t1i + t3r), c3f, s3f); // (t1+i*t3)W^3
    }
    __syncthreads();

    // radix-4 DIF stages, L = 64, 16, 4, on 2 planes
    #pragma unroll
    for (int sL = 0; sL < 3; sL++) {
        const int L = 64 >> (2 * sL);
        int j = tid & (L - 1);
        int base = ((tid - j) << 2) + j;
        float s1, c1;
        __sincosf(-(float)M_PI * 0.5f * (float)j / (float)L, &s1, &c1);
        float c2 = c1 * c1 - s1 * s1, s2 = 2.f * c1 * s1;
        float c3 = c2 * c1 - s2 * s1, s3 = c2 * s1 + s2 * c1;
        #pragma unroll
        for (int pl = 0; pl < 2; pl++) {
            float2 a  = bufs[pl][swz(base)];
            float2 bb = bufs[pl][swz(base + L)];
            float2 cc = bufs[pl][swz(base + 2 * L)];
            float2 dd = bufs[pl][swz(base + 3 * L)];
            float t0r = a.x + cc.x, t0i = a.y + cc.y;
            float t1r = a.x - cc.x, t1i = a.y - cc.y;
            float t2r = bb.x + dd.x, t2i = bb.y + dd.y;
            float t3r = bb.x - dd.x, t3i = bb.y - dd.y;
            float X0r = t0r + t2r, X0i = t0i + t2i;
            float X2r = t0r - t2r, X2i = t0i - t2i;
            float X1r = t1r + t3i, X1i = t1i - t3r;
            float X3r = t1r - t3i, X3i = t1i + t3r;
            bufs[pl][swz(base)]         = make_float2(X0r, X0i);
            bufs[pl][swz(base + L)]     = make_float2(X1r * c1 - X1i * s1, X1r * s1 + X1i * c1);
            bufs[pl][swz(base + 2 * L)] = make_float2(X2r * c2 - X2i * s2, X2r * s2 + X2i * c2);
            bufs[pl][swz(base + 3 * L)] = make_float2(X3r * c3 - X3i * s3, X3r * s3 + X3i * c3);
        }
        __syncthreads();
    }

    // last stage (L=1, twiddle-free) in registers, then write back for gather
    int i0 = swz(4 * tid);
    float2 A[2][4];
    #pragma unroll
    for (int pl = 0; pl < 2; pl++) {
        const float4* p4 = (const float4*)&bufs[pl][i0];
        float4 v0 = p4[0], v1 = p4[1];
        float t0r = v0.x + v1.x, t0i = v0.y + v1.y;
        float t1r = v0.x - v1.x, t1i = v0.y - v1.y;
        float t2r = v0.z + v1.z, t2i = v0.w + v1.w;
        float t3r = v0.z - v1.z, t3i = v0.w - v1.w;
        A[pl][0] = make_float2(t0r + t2r, t0i + t2i);
        A[pl][1] = make_float2(t1r + t3i, t1i - t3r);   // t1 - i*t3
        A[pl][2] = make_float2(t0r - t2r, t0i - t2i);
        A[pl][3] = make_float2(t1r - t3i, t1i + t3r);   // t1 + i*t3
    }
    // each 4-group is read only by its owning thread -> safe to overwrite now
    #pragma unroll
    for (int pl = 0; pl < 2; pl++)
        #pragma unroll
        for (int j = 0; j < 4; j++)
            bufs[pl][i0 + j] = A[pl][j];
    __syncthreads();

    // unpack via conjugate symmetry + scale + pack + uint4 stores
    const float sc  = 1.f / 64.f;    // planes 1,3 (direct)
    const float sc2 = 1.f / 128.f;   // planes 0,2 (un-halved symmetric sums)
    unsigned o0[4], o1[4], o2[4], o3[4];
    #pragma unroll
    for (int j = 0; j < 4; j++) {
        int p = 4 * tid + j;
        int pq = prt(p);
        float2 zap = A[0][j], zbp = A[1][j];
        float2 zaq = bufs[0][swz(pq)];
        float2 zbq = bufs[1][swz(pq)];
        // X0 = (Za[k] + conj(Za[N-k]))/2 ; X2 = -i(Za[k] - conj(Za[N-k]))/2
        float p0r = zap.x + zaq.x, p0i = zap.y - zaq.y;
        float dr  = zap.x - zaq.x, di  = zap.y + zaq.y;
        float p2r = di, p2i = -dr;
        o0[j] = pack2(p0r * sc2, p0i * sc2);
        o2[j] = pack2(p2r * sc2, p2i * sc2);
        o1[j] = pack2(zbp.x * sc, zbp.y * sc);      // X1 = Zb[k]
        o3[j] = pack2(zbq.x * sc, -zbq.y * sc);     // X3 = conj(Zb[N-k])
    }
    size_t qs = (size_t)BS * NN;
    size_t base = (((size_t)b * 4) * BS + d) * NN + 4 * tid;
    *(uint4*)(Xp + base)          = make_uint4(o0[0], o0[1], o0[2], o0[3]);
    *(uint4*)(Xp + base + qs)     = make_uint4(o1[0], o1[1], o1[2], o1[3]);
    *(uint4*)(Xp + base + 2 * qs) = make_uint4(o2[0], o2[1], o2[2], o2[3]);
    *(uint4*)(Xp + base + 3 * qs) = make_uint4(o3[0], o3[1], o3[2], o3[3]);
}

// ---------------------------------------------------------------------------
// Kernel 2b: one-time B prepack into flat [q][ch][j=384][dd=16] dwords.
// ---------------------------------------------------------------------------
__global__ void pack_b(const float* __restrict__ w, unsigned* __restrict__ Bp) {
    int ch = blockIdx.x, q = blockIdx.y;
    const float* wr = w + (size_t)q * BS * BS;
    const float* wi = w + (size_t)(4 + q) * BS * BS;
    size_t base = ((size_t)q * 12 + ch) * (384 * 16);
    for (int r = 0; r < 24; r++) {
        int idx = r * 256 + threadIdx.x;       // 0..6143
        int j = idx >> 4, dd = idx & 15;
        int h = j >> 1;
        int dg = ch * 16 + dd;
        float Wr = wr[(size_t)dg * BS + h];
        float Wi = wi[(size_t)dg * BS + h];
        Bp[base + idx] = (j & 1) ? pack2(Wi, Wr) : pack2(Wr, -Wi);
    }
}

// ---------------------------------------------------------------------------
// Kernel 3: FUSED complex MLP (R10 form — best measured). 512 threads =
// 8 j-waves; single 48 KB k-interleaved LDS panel shared for A then H.
// ---------------------------------------------------------------------------
__global__ __launch_bounds__(512) void fused_mlp(const unsigned* __restrict__ Ap,
                                                 const unsigned* __restrict__ Bp1,
                                                 const unsigned* __restrict__ Bp2,
                                                 const float* __restrict__ b1,
                                                 const float* __restrict__ b2,
                                                 unsigned* __restrict__ Yp) {
    __shared__ __align__(16) unsigned tl[12288];   // 48 KB shared panel

    const int mblk = blockIdx.x;   // 0..15 (64 m each)
    const int bq   = blockIdx.y;   // 0..255
    const int q    = bq & 3;
    const int tid  = threadIdx.x;
    const int wave = tid >> 6;     // 0..7: j-group, owns j = wave*48..+47
    const int lane = tid & 63;
    const int l15  = lane & 15;
    const int quad = lane >> 4;
    const int jw   = wave * 48;

    const size_t bstride = 384 * 16;   // dwords per (q,ch) slab
    const unsigned* b1_lane = Bp1 + (size_t)q * 12 * bstride + (jw + l15) * 16 + quad * 4;
    const unsigned* b2_lane = Bp2 + (size_t)q * 12 * bstride + (jw + l15) * 16 + quad * 4;

    // ---- stage A panel (192 rows x 64 cols) into k-interleaved LDS ----
    {
        const unsigned* abase = Ap + ((size_t)bq * BS) * NN + (size_t)mblk * 64;
        unsigned st[24];
        #pragma unroll
        for (int i = 0; i < 6; i++) {
            int r = (i * 8 + wave) * 4 + quad;
            const unsigned* gp = abase + (size_t)r * NN + l15;
            #pragma unroll
            for (int k = 0; k < 4; k++) st[i * 4 + k] = gp[16 * k];
        }
        #pragma unroll
        for (int i = 0; i < 6; i++) {
            int s = i * 8 + wave;
            unsigned* lp = &tl[s * 256 + quad];
            #pragma unroll
            for (int k = 0; k < 4; k++) lp[(l15 + 16 * k) * 4] = st[i * 4 + k];
        }
    }

    f32x4 acc[3][4];   // acc[tn][tm]
    #pragma unroll
    for (int i = 0; i < 3; i++)
        #pragma unroll
        for (int j = 0; j < 4; j++)
            acc[i][j] = (f32x4)0.f;

    __syncthreads();

    // ---- layer 1: 12 chunks; A-frags = 1 ds_read_b128 ----
    for (int ch = 0; ch < 12; ch++) {
        const unsigned* tp = &tl[(ch * 4 + quad) * 256];
        const unsigned* bp = b1_lane + ch * bstride;
        bf16x8 af[4], bfr[3];
        #pragma unroll
        for (int tm = 0; tm < 4; tm++)
            af[tm] = *(const bf16x8*)(tp + (tm * 16 + l15) * 4);
        #pragma unroll
        for (int tn = 0; tn < 3; tn++) {
            union { uint4 u4; bf16x8 v; } bu;
            bu.u4 = *(const uint4*)(bp + tn * 256);
            bfr[tn] = bu.v;
        }
        #pragma unroll
        for (int tn = 0; tn < 3; tn++)
            #pragma unroll
            for (int tm = 0; tm < 4; tm++)
                acc[tn][tm] = __builtin_amdgcn_mfma_f32_16x16x32_bf16(bfr[tn], af[tm], acc[tn][tm], 0, 0, 0);
    }

    __syncthreads();   // all waves done reading A before H overwrites

    // ---- epilogue 1: bias + ReLU -> bf16 pack -> H into same LDS ----
    #pragma unroll
    for (int tn = 0; tn < 3; tn++) {
        int hg = (jw >> 1) + tn * 8 + quad * 2;   // rows hg, hg+1
        float b0r = b1[q * BS + hg];
        float b0i = b1[768 + q * BS + hg];
        float b1r_ = b1[q * BS + hg + 1];
        float b1i_ = b1[768 + q * BS + hg + 1];
        #pragma unroll
        for (int tm = 0; tm < 4; tm++) {
            int c = tm * 16 + l15;
            f32x4 a = acc[tn][tm];
            float v0 = fmaxf(a[0] + b0r, 0.f);
            float v1 = fmaxf(a[1] + b0i, 0.f);
            float v2 = fmaxf(a[2] + b1r_, 0.f);
            float v3 = fmaxf(a[3] + b1i_, 0.f);
            unsigned* hp = &tl[(hg >> 2) * 256 + c * 4 + (hg & 3)];
            *(uint2*)hp = make_uint2(pack2(v0, v1), pack2(v2, v3));
            acc[tn][tm] = (f32x4)0.f;
        }
    }
    __syncthreads();

    // ---- layer 2: 12 chunks over H-LDS ----
    for (int ch = 0; ch < 12; ch++) {
        const unsigned* tp = &tl[(ch * 4 + quad) * 256];
        const unsigned* bp = b2_lane + ch * bstride;
        bf16x8 af[4], bfr[3];
        #pragma unroll
        for (int tm = 0; tm < 4; tm++)
            af[tm] = *(const bf16x8*)(tp + (tm * 16 + l15) * 4);
        #pragma unroll
        for (int tn = 0; tn < 3; tn++) {
            union { uint4 u4; bf16x8 v; } bu;
            bu.u4 = *(const uint4*)(bp + tn * 256);
            bfr[tn] = bu.v;
        }
        #pragma unroll
        for (int tn = 0; tn < 3; tn++)
            #pragma unroll
            for (int tm = 0; tm < 4; tm++)
                acc[tn][tm] = __builtin_amdgcn_mfma_f32_16x16x32_bf16(bfr[tn], af[tm], acc[tn][tm], 0, 0, 0);
    }

    // ---- epilogue 2: bias + softshrink -> Y plane stores ----
    #pragma unroll
    for (int tn = 0; tn < 3; tn++) {
        int hg = (jw >> 1) + tn * 8 + quad * 2;
        float b0r = b2[q * BS + hg];
        float b0i = b2[768 + q * BS + hg];
        float b1r_ = b2[q * BS + hg + 1];
        float b1i_ = b2[768 + q * BS + hg + 1];
        size_t row0 = ((size_t)bq * BS + hg) * NN + (size_t)mblk * 64;
        #pragma unroll
        for (int tm = 0; tm < 4; tm++) {
            int mcol = tm * 16 + l15;
            f32x4 a = acc[tn][tm];
            float v0 = a[0] + b0r, v1 = a[1] + b0i;
            float v2 = a[2] + b1r_, v3 = a[3] + b1i_;
            v0 = (v0 > LAM) ? (v0 - LAM) : ((v0 < -LAM) ? (v0 + LAM) : 0.f);
            v1 = (v1 > LAM) ? (v1 - LAM) : ((v1 < -LAM) ? (v1 + LAM) : 0.f);
            v2 = (v2 > LAM) ? (v2 - LAM) : ((v2 < -LAM) ? (v2 + LAM) : 0.f);
            v3 = (v3 > LAM) ? (v3 - LAM) : ((v3 < -LAM) ? (v3 + LAM) : 0.f);
            Yp[row0 + mcol]      = pack2(v0, v1);
            Yp[row0 + NN + mcol] = pack2(v2, v3);
        }
    }
}

// ---------------------------------------------------------------------------
// Kernel 4: inverse with Hermitian-part packing: symmetrize S over
// (N-k, 4-u), pack Wa = Sh0 + i*Sh2 and Wb = Sh1 -> 2 inverse FFTs (was 4);
// V0 = Re(ifft Wa), V2 = Im(ifft Wa), V1 = ifft(Wb), V3 = conj(V1);
// y_q reconstructed + residual. Last stage (L=256) folded into the tail.
// ---------------------------------------------------------------------------
__global__ void inv_fft(const float* __restrict__ x,
                        const unsigned* __restrict__ Yp,
                        float* __restrict__ out) {
    __shared__ float2 bufs[4][1024];
    int d = blockIdx.x, b = blockIdx.y, tid = threadIdx.x;

    // load all 4 planes at positions p = 4t..4t+3
    float2 S[4][4];
    size_t qs = (size_t)BS * NN;
    size_t rowb = (((size_t)b * 4) * BS + d) * NN + 4 * tid;
    #pragma unroll
    for (int u = 0; u < 4; u++) {
        uint4 v = *(const uint4*)(Yp + rowb + (size_t)u * qs);
        S[u][0] = make_float2(bflo(v.x), bfhi(v.x));
        S[u][1] = make_float2(bflo(v.y), bfhi(v.y));
        S[u][2] = make_float2(bflo(v.z), bfhi(v.z));
        S[u][3] = make_float2(bflo(v.w), bfhi(v.w));
    }
    // write raw S to LDS for partner gather
    int i0 = swz(4 * tid);
    #pragma unroll
    for (int u = 0; u < 4; u++)
        #pragma unroll
        for (int j = 0; j < 4; j++)
            bufs[u][i0 + j] = S[u][j];
    __syncthreads();

    // gather partners, build un-halved Hermitian parts:
    // Wa = (S0[p]+conj(S0[pp])) + i(S2[p]+conj(S2[pp])) ; Wb = S1[p]+conj(S3[pp])
    float2 Wa[4], Wb[4];
    #pragma unroll
    for (int j = 0; j < 4; j++) {
        int p = 4 * tid + j;
        int pq = prt(p);
        float2 s0q = bufs[0][swz(pq)];
        float2 s2q = bufs[2][swz(pq)];
        float2 s3q = bufs[3][swz(pq)];
        float h0r = S[0][j].x + s0q.x, h0i = S[0][j].y - s0q.y;
        float h2r = S[2][j].x + s2q.x, h2i = S[2][j].y - s2q.y;
        Wa[j] = make_float2(h0r - h2i, h0i + h2r);
        Wb[j] = make_float2(S[1][j].x + s3q.x, S[1][j].y - s3q.y);
    }
    __syncthreads();   // done reading S before overwriting planes 0,1

    // first DIT stage (twiddle-free, 4-consec) in registers -> LDS planes 0,1
    #pragma unroll
    for (int pl = 0; pl < 2; pl++) {
        float2 w0 = pl ? Wb[0] : Wa[0], w1 = pl ? Wb[1] : Wa[1];
        float2 w2 = pl ? Wb[2] : Wa[2], w3 = pl ? Wb[3] : Wa[3];
        float t0r = w0.x + w2.x, t0i = w0.y + w2.y;
        float t1r = w0.x - w2.x, t1i = w0.y - w2.y;
        float t2r = w1.x + w3.x, t2i = w1.y + w3.y;
        float t3r = w1.x - w3.x, t3i = w1.y - w3.y;
        bufs[pl][i0 + 0] = make_float2(t0r + t2r, t0i + t2i);
        bufs[pl][i0 + 1] = make_float2(t1r - t3i, t1i + t3r);  // t1 + i*t3
        bufs[pl][i0 + 2] = make_float2(t0r - t2r, t0i - t2i);
        bufs[pl][i0 + 3] = make_float2(t1r + t3i, t1i - t3r);  // t1 - i*t3
    }
    __syncthreads();

    // radix-4 DIT stages, L = 4, 16, 64, on 2 planes (conjugate twiddles)
    #pragma unroll
    for (int sL = 0; sL < 3; sL++) {
        const int L = 4 << (2 * sL);
        int j = tid & (L - 1);
        int base = ((tid - j) << 2) + j;
        float s1, c1;
        __sincosf((float)M_PI * 0.5f * (float)j / (float)L, &s1, &c1);
        float c2 = c1 * c1 - s1 * s1, s2 = 2.f * c1 * s1;
        float c3 = c2 * c1 - s2 * s1, s3 = c2 * s1 + s2 * c1;
        #pragma unroll
        for (int pl = 0; pl < 2; pl++) {
            float2 y0 = bufs[pl][swz(base)];
            float2 y1 = bufs[pl][swz(base + L)];
            float2 y2 = bufs[pl][swz(base + 2 * L)];
            float2 y3 = bufs[pl][swz(base + 3 * L)];
            float A1r = y1.x * c1 - y1.y * s1, A1i = y1.x * s1 + y1.y * c1;
            float A2r = y2.x * c2 - y2.y * s2, A2i = y2.x * s2 + y2.y * c2;
            float A3r = y3.x * c3 - y3.y * s3, A3i = y3.x * s3 + y3.y * c3;
            float t0r = y0.x + A2r, t0i = y0.y + A2i;
            float t1r = y0.x - A2r, t1i = y0.y - A2i;
            float t2r = A1r + A3r, t2i = A1i + A3i;
            float t3r = A1r - A3r, t3i = A1i - A3i;
            bufs[pl][swz(base)]         = make_float2(t0r + t2r, t0i + t2i);
            bufs[pl][swz(base + L)]     = make_float2(t1r - t3i, t1i + t3r);
            bufs[pl][swz(base + 2 * L)] = make_float2(t0r - t2r, t0i - t2i);
            bufs[pl][swz(base + 3 * L)] = make_float2(t1r + t3i, t1i - t3r);
        }
        __syncthreads();
    }

    // folded L=256 stage (full complex) + y_q reconstruction + residual
    float s1f, c1f;
    __sincosf((float)M_PI * 0.5f * (float)tid / 256.f, &s1f, &c1f);
    float c2f = c1f * c1f - s1f * s1f, s2f = 2.f * c1f * s1f;
    float c3f = c2f * c1f - s2f * s1f, s3f = c2f * s1f + s2f * c1f;

    float2 Va[4], Vb[4];
    #pragma unroll
    for (int pl = 0; pl < 2; pl++) {
        float2 y0 = bufs[pl][swz(tid)];
        float2 y1 = bufs[pl][swz(tid + 256)];
        float2 y2 = bufs[pl][swz(tid + 512)];
        float2 y3 = bufs[pl][swz(tid + 768)];
        float2 A1 = cmul(y1, c1f, s1f);
        float2 A2 = cmul(y2, c2f, s2f);
        float2 A3 = cmul(y3, c3f, s3f);
        float t0r = y0.x + A2.x, t0i = y0.y + A2.y;
        float t1r = y0.x - A2.x, t1i = y0.y - A2.y;
        float t2r = A1.x + A3.x, t2i = A1.y + A3.y;
        float t3r = A1.x - A3.x, t3i = A1.y - A3.y;
        float2* V = pl ? Vb : Va;
        V[0] = make_float2(t0r + t2r, t0i + t2i);            // n = tid
        V[1] = make_float2(t1r - t3i, t1i + t3r);            // n = tid+256
        V[2] = make_float2(t0r - t2r, t0i - t2i);            // n = tid+512
        V[3] = make_float2(t1r + t3i, t1i - t3r);            // n = tid+768
    }

    const float sc = 1.f / 128.f;   // (1/64 ortho) x (1/2 un-halved Hermitian)
    size_t row0 = (((size_t)b * 4 + 0) * BS + d) * NN;
    size_t row1 = (((size_t)b * 4 + 1) * BS + d) * NN;
    size_t row2 = (((size_t)b * 4 + 2) * BS + d) * NN;
    size_t row3 = (((size_t)b * 4 + 3) * BS + d) * NN;
    #pragma unroll
    for (int k = 0; k < 4; k++) {
        int n = tid + 256 * k;
        float V0 = Va[k].x, V2 = Va[k].y;
        float R1 = Vb[k].x, I1 = Vb[k].y;
        out[row0 + n] = (V0 + V2 + 2.f * R1) * sc + x[row0 + n];
        out[row1 + n] = (V0 - V2 - 2.f * I1) * sc + x[row1 + n];
        out[row2 + n] = (V0 + V2 - 2.f * R1) * sc + x[row2 + n];
        out[row3 + n] = (V0 - V2 + 2.f * I1) * sc + x[row3 + n];
    }
}

// ---------------------------------------------------------------------------
extern "C" void kernel_launch(void* const* d_in, const int* in_sizes, int n_in,
                              void* d_out, int out_size, void* d_ws, size_t ws_size,
                              hipStream_t stream) {
    const float* x     = (const float*)d_in[0];
    const float* w1    = (const float*)d_in[1];
    const float* w2    = (const float*)d_in[2];
    const float* b1    = (const float*)d_in[3];
    const float* b2    = (const float*)d_in[4];
    const float* gamma = (const float*)d_in[5];
    const float* beta  = (const float*)d_in[6];

    unsigned* Xp = (unsigned*)d_ws;
    float* mu    = (float*)d_ws + (size_t)BB * CC * NN;
    float* rstd  = mu + (size_t)BB * NN;
    unsigned* Bp1 = (unsigned*)(rstd + (size_t)BB * NN);
    unsigned* Bp2 = Bp1 + (size_t)4 * 12 * 384 * 16;
    unsigned* Yp = Xp;   // layer-2 output overwrites X region (disjoint m-cols per block)

    pack_b<<<dim3(12, 4), 256, 0, stream>>>(w1, Bp1);
    pack_b<<<dim3(12, 4), 256, 0, stream>>>(w2, Bp2);
    ln_stats<<<dim3(NN / 256, BB), 512, 0, stream>>>(x, mu, rstd);
    fwd_fft<<<dim3(BS, BB), 256, 0, stream>>>(x, mu, rstd, gamma, beta, Xp);
    fused_mlp<<<dim3(16, 256), 512, 0, stream>>>(Xp, Bp1, Bp2, b1, b2, Yp);
    inv_fft<<<dim3(BS, BB), 256, 0, stream>>>(x, Yp, (float*)d_out);
}